// Round 7
// baseline (549.683 us; speedup 1.0000x reference)
//
#include <hip/hip_runtime.h>
#include <hip/hip_bf16.h>
#include <math.h>
#include <stddef.h>
#include <stdint.h>

typedef __hip_bfloat16 bf16;
typedef short bf16x8 __attribute__((ext_vector_type(8)));
typedef float f32x4 __attribute__((ext_vector_type(4)));

#define CS 2048   // S
#define CD 768    // D
#define CH 12     // H
#define CDH 64    // DH
#define CF 3072   // F
#define CW 256    // W
#define CL 2      // L
#define QKVN 2304 // 3*D fused qkv width
#define SDC ((size_t)CS * CD)
#define EPS_LD 136  // epilogue LDS stride (bf16 elems)

// ---------------- async global->LDS, 16B per lane ----------------
__device__ __forceinline__ void gload_lds16(const bf16* g, bf16* l) {
  __builtin_amdgcn_global_load_lds(
      (const __attribute__((address_space(1))) void*)g,
      (__attribute__((address_space(3))) void*)l, 16, 0, 0);
}

__device__ __forceinline__ unsigned short f2bu(float v) {
  bf16 b = __float2bfloat16(v);
  return *(unsigned short*)&b;
}
__device__ __forceinline__ float bu2f(unsigned short u) {
  bf16 b = *(bf16*)&u;
  return __bfloat162float(b);
}

// ---------------- block reduction, NW waves ----------------
template<int NW>
__device__ __forceinline__ float block_reduce_sum(float v, float* buf) {
  #pragma unroll
  for (int off = 32; off > 0; off >>= 1) v += __shfl_down(v, off, 64);
  __syncthreads();
  if ((threadIdx.x & 63) == 0) buf[threadIdx.x >> 6] = v;
  __syncthreads();
  float s = buf[0];
  #pragma unroll
  for (int w = 1; w < NW; ++w) s += buf[w];
  return s;
}

// ---------------- fused: all-weights transpose->bf16  +  embedding gather + LN ----
__global__ __launch_bounds__(256) void prep_kernel(
    const float* __restrict__ Wqkv, const float* __restrict__ Wo,
    const float* __restrict__ W1, const float* __restrict__ W2,
    bf16* __restrict__ WqkvT, bf16* __restrict__ WoT,
    bf16* __restrict__ W1T, bf16* __restrict__ W2T,
    const int* __restrict__ ids, const int* __restrict__ mask,
    const float* __restrict__ wemb, const float* __restrict__ pemb,
    const float* __restrict__ temb, const float* __restrict__ gs,
    const float* __restrict__ gb, float* __restrict__ x, bf16* __restrict__ xb) {
  __shared__ float tile[64][33];
  __shared__ float red[4];
  int b = blockIdx.x;
  if (b < 6912) {
    // -------- weight transpose (fp32 K x N -> bf16 N x K) --------
    const float* src; bf16* dst; int K, N, t;
    if (b < 1728) {
      int mat = b / 288; t = b % 288; K = 768; N = 768;
      src = Wqkv + (size_t)mat * 768 * 768; dst = WqkvT + (size_t)mat * 768 * 768;
    } else if (b < 2304) {
      b -= 1728; int mat = b / 288; t = b % 288; K = 768; N = 768;
      src = Wo + (size_t)mat * 768 * 768; dst = WoT + (size_t)mat * 768 * 768;
    } else if (b < 4608) {
      b -= 2304; int mat = b / 1152; t = b % 1152; K = 768; N = 3072;
      src = W1 + (size_t)mat * 768 * 3072; dst = W1T + (size_t)mat * 768 * 3072;
    } else {
      b -= 4608; int mat = b / 1152; t = b % 1152; K = 3072; N = 768;
      src = W2 + (size_t)mat * 3072 * 768; dst = W2T + (size_t)mat * 3072 * 768;
    }
    int nt = N / 32;
    int bn = (t % nt) * 32, bk = (t / nt) * 64;
    int tx = threadIdx.x & 31, ty = (threadIdx.x >> 5);   // ty 0..7
    #pragma unroll
    for (int i = 0; i < 8; ++i)
      tile[ty + i * 8][tx] = src[(size_t)(bk + ty + i * 8) * N + bn + tx];
    __syncthreads();
    #pragma unroll
    for (int i = 0; i < 4; ++i) {
      int n = ty + i * 8;
      if (n < 32) {
        ushort2 pk;
        pk.x = f2bu(tile[2 * tx][n]);
        pk.y = f2bu(tile[2 * tx + 1][n]);
        *(ushort2*)&dst[(size_t)(bn + n) * K + bk + 2 * tx] = pk;
      }
    }
  } else {
    // -------- embedding + LN (vectorized: 192 lanes x float4) --------
    int srow = b - 6912;
    int t = threadIdx.x;
    float ps = 0.f;
    for (int i = t; i <= srow; i += 256) ps += (float)mask[i];
    float tot = block_reduce_sum<4>(ps, red);
    long long pid = (long long)((int)(tot + 0.5f) * mask[srow] + 1);
    long long id = ids[srow];
    float4 v = {0.f, 0.f, 0.f, 0.f};
    if (t < 192) {
      int d = t * 4;
      float4 a = *(const float4*)&wemb[id * CD + d];
      float4 p = *(const float4*)&pemb[pid * CD + d];
      float4 tm = *(const float4*)&temb[d];
      v.x = a.x + p.x + tm.x; v.y = a.y + p.y + tm.y;
      v.z = a.z + p.z + tm.z; v.w = a.w + p.w + tm.w;
    }
    float sum = block_reduce_sum<4>(v.x + v.y + v.z + v.w, red);
    float mean = sum * (1.0f / CD);
    float cx = v.x - mean, cy = v.y - mean, cz = v.z - mean, cw = v.w - mean;
    float sqv = (t < 192) ? (cx * cx + cy * cy + cz * cz + cw * cw) : 0.f;
    float sq = block_reduce_sum<4>(sqv, red);
    float rstd = rsqrtf(sq * (1.0f / CD) + 1e-5f);
    if (t < 192) {
      int d = t * 4;
      float4 g4 = *(const float4*)&gs[d];
      float4 b4 = *(const float4*)&gb[d];
      float4 o;
      o.x = cx * rstd * g4.x + b4.x;
      o.y = cy * rstd * g4.y + b4.y;
      o.z = cz * rstd * g4.z + b4.z;
      o.w = cw * rstd * g4.w + b4.w;
      *(float4*)&x[(size_t)srow * CD + d] = o;
      ushort4 pk;
      pk.x = f2bu(o.x); pk.y = f2bu(o.y); pk.z = f2bu(o.z); pk.w = f2bu(o.w);
      *(ushort4*)&xb[(size_t)srow * CD + d] = pk;
    }
  }
}

// ---------------- MFMA GEMM: 64(M)x128(N) tile, 2 waves, BK=64 ----------------
// Depth-3 pipeline with counted vmcnt (T4): 3 LDS buffers, 2 tiles prefetched
// ahead; per-iter wait is vmcnt(12) (next tile's 12 loads stay in flight), only
// the last iter drains to 0. Prefetch->use distance = 2 MFMA phases >= L2
// latency -> ~zero exposed staging latency. Hazards: top-of-iter barrier is
// passed after all waves' compute(t-1), so re-staging (t-1)'s buffer after it
// is race-free; vmcnt retires oldest-first (m135) so vmcnt(12) => tile t done.
template<int GELU, int SPLITS, int TRANS>
__device__ __forceinline__ void gemm_body(
    const bf16* __restrict__ A, const bf16* __restrict__ Bt,
    const float* __restrict__ bias, bf16* __restrict__ Cout,
    bf16* __restrict__ vTout, int M, int N, int Ktot, char* smem,
    int bx, int by) {
  // layout: As[3] @ [0,24K)  Bs[3] @ [24K,72K)
  bf16* As = (bf16*)smem;
  bf16* Bs = (bf16*)(smem + 24576);
  bf16* eps = (bf16*)smem;                   // epilogue tile, aliases staging
  const int tid = threadIdx.x;
  const int wave = tid >> 6, lane = tid & 63;
  const int m0 = by * 64, n0 = bx * 128;
  const int wn = wave * 64;
  const int quad = lane >> 4, rsel = lane & 15;
  const int rx = rsel & 7;
  const int r_in = lane >> 3;          // staging row within op (0..7)
  const int chunk = lane & 7;          // staging LDS chunk c'
  const int gchunk = chunk ^ r_in;     // global chunk to load
  const int Klen = Ktot / SPLITS;
  const int koff = (SPLITS > 1) ? blockIdx.z * Klen : 0;
  const int nt = Klen / 64;

  f32x4 acc[4][4] = {};

  auto STAGE = [&](int buf, int t) {
    const int kk = koff + t * 64;
    bf16* Asb = As + buf * 4096;
    bf16* Bsb = Bs + buf * 8192;
    #pragma unroll
    for (int i = 0; i < 12; ++i) {
      int op = wave * 12 + i;
      if (op < 8) {
        int row = op * 8 + r_in;
        gload_lds16(A + (size_t)(m0 + row) * Ktot + kk + gchunk * 8, &Asb[op * 512]);
      } else {
        int row = (op - 8) * 8 + r_in;
        gload_lds16(Bt + (size_t)(n0 + row) * Ktot + kk + gchunk * 8, &Bsb[(op - 8) * 512]);
      }
    }
  };

  // prologue: stage tiles 0 and 1 (24 loads per wave in flight)
  STAGE(0, 0);
  STAGE(1, 1);

  int cur = 0;
  for (int t = 0; t < nt; ++t) {
    // wait for tile t's 12 loads (leave tile t+1's 12 in flight if staged)
    if (t + 1 < nt) __asm__ volatile("s_waitcnt vmcnt(12)" ::: "memory");
    else            __asm__ volatile("s_waitcnt vmcnt(0)" ::: "memory");
    __builtin_amdgcn_s_barrier();
    __builtin_amdgcn_sched_barrier(0);
    if (t + 2 < nt) STAGE(cur == 0 ? 2 : cur - 1, t + 2);  // (t+2)%3 buffer
    __builtin_amdgcn_sched_barrier(0);
    const bf16* Asb = As + cur * 4096;
    const bf16* Bsb = Bs + cur * 8192;
    #pragma unroll
    for (int kh = 0; kh < 2; ++kh) {
      bf16x8 af[4], bfr[4];
      int cq = ((kh << 2) | quad);
      #pragma unroll
      for (int i = 0; i < 4; ++i)
        af[i] = *(const bf16x8*)&Asb[(i * 16 + rsel) * 64 + (cq ^ rx) * 8];
      #pragma unroll
      for (int j = 0; j < 4; ++j)
        bfr[j] = *(const bf16x8*)&Bsb[(wn + j * 16 + rsel) * 64 + (cq ^ rx) * 8];
      #pragma unroll
      for (int i = 0; i < 4; ++i)
        #pragma unroll
        for (int j = 0; j < 4; ++j) {
          if (TRANS)
            acc[i][j] = __builtin_amdgcn_mfma_f32_16x16x32_bf16(af[i], bfr[j], acc[i][j], 0, 0, 0);
          else
            acc[i][j] = __builtin_amdgcn_mfma_f32_16x16x32_bf16(bfr[j], af[i], acc[i][j], 0, 0, 0);
        }
    }
    cur = (cur == 2) ? 0 : cur + 1;
  }
  __syncthreads();   // all waves done reading staging LDS before eps overwrite

  if (!TRANS) {
    #pragma unroll
    for (int j = 0; j < 4; ++j) {
      int cb = wn + j * 16 + quad * 4;
      float4 bv = {0.f, 0.f, 0.f, 0.f};
      if (SPLITS == 1 || blockIdx.z == 0) bv = *(const float4*)&bias[n0 + cb];
      #pragma unroll
      for (int i = 0; i < 4; ++i) {
        float v0 = acc[i][j][0] + bv.x;
        float v1 = acc[i][j][1] + bv.y;
        float v2 = acc[i][j][2] + bv.z;
        float v3 = acc[i][j][3] + bv.w;
        if (GELU) {
          v0 = 0.5f * v0 * (1.0f + erff(v0 * 0.70710678118654752f));
          v1 = 0.5f * v1 * (1.0f + erff(v1 * 0.70710678118654752f));
          v2 = 0.5f * v2 * (1.0f + erff(v2 * 0.70710678118654752f));
          v3 = 0.5f * v3 * (1.0f + erff(v3 * 0.70710678118654752f));
        }
        ushort4 pk;
        pk.x = f2bu(v0); pk.y = f2bu(v1); pk.z = f2bu(v2); pk.w = f2bu(v3);
        *(ushort4*)&eps[(i * 16 + rsel) * EPS_LD + cb] = pk;
      }
    }
    __syncthreads();
    const size_t zb = (SPLITS > 1) ? (size_t)blockIdx.z * M * N : 0;
    #pragma unroll
    for (int it = 0; it < 8; ++it) {
      int row = it * 8 + (tid >> 4);
      int c = tid & 15;
      bf16x8 v = *(const bf16x8*)&eps[row * EPS_LD + c * 8];
      *(bf16x8*)&Cout[zb + (size_t)(m0 + row) * N + n0 + c * 8] = v;
    }
  } else {
    #pragma unroll
    for (int j = 0; j < 4; ++j) {
      float bv = bias[n0 + wn + j * 16 + rsel];
      #pragma unroll
      for (int i = 0; i < 4; ++i) {
        ushort4 pk;
        pk.x = f2bu(acc[i][j][0] + bv);
        pk.y = f2bu(acc[i][j][1] + bv);
        pk.z = f2bu(acc[i][j][2] + bv);
        pk.w = f2bu(acc[i][j][3] + bv);
        *(ushort4*)&eps[(wn + j * 16 + rsel) * 72 + i * 16 + quad * 4] = pk;
      }
    }
    __syncthreads();
    #pragma unroll
    for (int it = 0; it < 8; ++it) {
      int row = it * 16 + (tid >> 3);   // n-local (dh index), 0..127
      int c = tid & 7;                  // 16B chunk along M
      bf16x8 v = *(const bf16x8*)&eps[row * 72 + c * 8];
      *(bf16x8*)&vTout[(size_t)(n0 - 1536 + row) * CS + m0 + c * 8] = v;
    }
  }
}

template<int GELU, int SPLITS, int VTFUSE>
__global__ __launch_bounds__(128, 1) void gemm_mfma(
    const bf16* __restrict__ A, const bf16* __restrict__ Bt,
    const float* __restrict__ bias, bf16* __restrict__ Cout,
    bf16* __restrict__ vTout, int M, int N, int Ktot) {
  // 3-deep staging 72KB; TRANS0 eps 17408B; TRANS1 eps 18432B (alias)
  __shared__ __align__(16) char smem[73728];
  int nx = gridDim.x, ny = gridDim.y;
  int nwg = nx * ny;
  int orig = blockIdx.x + blockIdx.y * nx;
  int bx, by;
  if (nwg & 7) { bx = blockIdx.x; by = blockIdx.y; }
  else {
    int q8 = nwg >> 3;
    int nid = (orig & 7) * q8 + (orig >> 3);
    bx = nid / ny; by = nid - bx * ny;
  }
  if (VTFUSE && bx * 128 >= 1536)
    gemm_body<0, 1, 1>(A, Bt, bias, Cout, vTout, M, N, Ktot, smem, bx, by);
  else
    gemm_body<GELU, SPLITS, 0>(A, Bt, bias, Cout, vTout, M, N, Ktot, smem, bx, by);
}

// ---------------- MFMA flash attention v2 (banded), LDS-staged K/V ----------------
__global__ __launch_bounds__(256) void attn_mfma(
    const bf16* __restrict__ qkv, const bf16* __restrict__ vT,
    const int* __restrict__ mask, bf16* __restrict__ ctx) {
  __shared__ __align__(16) bf16 Ks[64 * 64];
  __shared__ __align__(16) bf16 Vs[64 * 64];
  __shared__ __align__(16) bf16 Ps[4][16][72];
  const int h = blockIdx.y;
  const int q0 = blockIdx.x * 64;
  const int tid = threadIdx.x;
  const int wv = tid >> 6, lane = tid & 63;
  const int quad = lane >> 4, rsel = lane & 15;
  const int rx = rsel & 7;
  const int qw = q0 + wv * 16;
  const int r_in = lane >> 3, chunk = lane & 7, gchunk = chunk ^ r_in;

  const bf16* qp = &qkv[(size_t)(qw + rsel) * QKVN + h * CDH + quad * 8];
  bf16x8 qf0 = *(const bf16x8*)qp;
  bf16x8 qf1 = *(const bf16x8*)(qp + 32);

  float mi[4], li[4];
  f32x4 o[4] = {};
  #pragma unroll
  for (int r = 0; r < 4; ++r) { mi[r] = -1e30f; li[r] = 0.f; }

  #pragma unroll 1
  for (int kt = 0; kt < 9; ++kt) {
    int kbase = q0 - CW + kt * 64;
    bool tile_in = (kbase + 63 >= 0) && (kbase < CS);
    if (tile_in) {
      #pragma unroll
      for (int i = 0; i < 4; ++i) {
        int op = wv * 4 + i;     // 0..15: 8 K ops + 8 V ops
        if (op < 8) {
          int krow = min(max(kbase + op * 8 + r_in, 0), CS - 1);
          gload_lds16(&qkv[(size_t)krow * QKVN + 768 + h * CDH + gchunk * 8], &Ks[op * 512]);
        } else {
          int vop = op - 8;
          int kc = min(max(kbase + gchunk * 8, 0), CS - 8);
          gload_lds16(&vT[(size_t)(h * CDH + vop * 8 + r_in) * CS + kc], &Vs[vop * 512]);
        }
      }
    }
    __syncthreads();
    bool active = tile_in && (kbase + 63 >= qw - CW) && (kbase <= qw + 15 + CW);
    if (active) {
      f32x4 sc[4];
      #pragma unroll
      for (int nt = 0; nt < 4; ++nt) {
        const bf16* kp = &Ks[(nt * 16 + rsel) * 64];
        bf16x8 kf0 = *(const bf16x8*)(kp + (quad ^ rx) * 8);
        bf16x8 kf1 = *(const bf16x8*)(kp + ((quad + 4) ^ rx) * 8);
        f32x4 z = {};
        __builtin_amdgcn_s_setprio(1);
        z = __builtin_amdgcn_mfma_f32_16x16x32_bf16(qf0, kf0, z, 0, 0, 0);
        z = __builtin_amdgcn_mfma_f32_16x16x32_bf16(qf1, kf1, z, 0, 0, 0);
        __builtin_amdgcn_s_setprio(0);
        sc[nt] = z;
      }
      float mx[4] = {-1e30f, -1e30f, -1e30f, -1e30f};
      #pragma unroll
      for (int nt = 0; nt < 4; ++nt) {
        int pp = kbase + nt * 16 + rsel;
        int ppc = min(max(pp, 0), CS - 1);
        bool kvld = (pp >= 0) && (pp < CS) && (mask[ppc] != 0);
        #pragma unroll
        for (int r = 0; r < 4; ++r) {
          int qr = qw + quad * 4 + r;
          float s = sc[nt][r] * 0.125f;
          bool band = (pp >= qr - CW) && (pp <= qr + CW);
          s = (kvld && band) ? s : -1e9f;
          sc[nt][r] = s;
          mx[r] = fmaxf(mx[r], s);
        }
      }
      #pragma unroll
      for (int r = 0; r < 4; ++r) {
        #pragma unroll
        for (int off = 1; off < 16; off <<= 1)
          mx[r] = fmaxf(mx[r], __shfl_xor(mx[r], off, 64));
      }
      float al[4], rs[4] = {};
      #pragma unroll
      for (int r = 0; r < 4; ++r) {
        float mn = fmaxf(mi[r], mx[r]);
        al[r] = __expf(mi[r] - mn);
        mi[r] = mn;
      }
      #pragma unroll
      for (int nt = 0; nt < 4; ++nt)
        #pragma unroll
        for (int r = 0; r < 4; ++r) {
          float p = __expf(sc[nt][r] - mi[r]);
          sc[nt][r] = p;
          rs[r] += p;
        }
      #pragma unroll
      for (int r = 0; r < 4; ++r) {
        #pragma unroll
        for (int off = 1; off < 16; off <<= 1)
          rs[r] += __shfl_xor(rs[r], off, 64);
        li[r] = li[r] * al[r] + rs[r];
      }
      #pragma unroll
      for (int d = 0; d < 4; ++d)
        #pragma unroll
        for (int r = 0; r < 4; ++r) o[d][r] *= al[r];
      #pragma unroll
      for (int nt = 0; nt < 4; ++nt)
        #pragma unroll
        for (int r = 0; r < 4; ++r)
          Ps[wv][quad * 4 + r][nt * 16 + rsel] = __float2bfloat16(sc[nt][r]);
      __asm__ volatile("s_waitcnt lgkmcnt(0)" ::: "memory");
      __builtin_amdgcn_sched_barrier(0);
      bf16x8 pf0 = *(const bf16x8*)&Ps[wv][rsel][quad * 8];
      bf16x8 pf1 = *(const bf16x8*)&Ps[wv][rsel][32 + quad * 8];
      #pragma unroll
      for (int d = 0; d < 4; ++d) {
        const bf16* vr = &Vs[(d * 16 + rsel) * 64];
        bf16x8 vf0 = *(const bf16x8*)(vr + (quad ^ rx) * 8);
        bf16x8 vf1 = *(const bf16x8*)(vr + ((quad + 4) ^ rx) * 8);
        __builtin_amdgcn_s_setprio(1);
        o[d] = __builtin_amdgcn_mfma_f32_16x16x32_bf16(pf0, vf0, o[d], 0, 0, 0);
        o[d] = __builtin_amdgcn_mfma_f32_16x16x32_bf16(pf1, vf1, o[d], 0, 0, 0);
        __builtin_amdgcn_s_setprio(0);
      }
    }
    __syncthreads();
  }

  float inv[4];
  #pragma unroll
  for (int r = 0; r < 4; ++r) inv[r] = 1.0f / li[r];
  #pragma unroll
  for (int d = 0; d < 4; ++d)
    #pragma unroll
    for (int r = 0; r < 4; ++r)
      Ps[wv][quad * 4 + r][d * 16 + rsel] = __float2bfloat16(o[d][r] * inv[r]);
  __asm__ volatile("s_waitcnt lgkmcnt(0)" ::: "memory");
  __builtin_amdgcn_sched_barrier(0);
  #pragma unroll
  for (int it = 0; it < 2; ++it) {
    int row = it * 8 + (lane >> 3);
    bf16x8 vv = *(const bf16x8*)&Ps[wv][row][(lane & 7) * 8];
    *(bf16x8*)&ctx[(size_t)(qw + row) * CD + h * CDH + (lane & 7) * 8] = vv;
  }
}

// ---------------- xout = LN(xin + sum_p g[p](bf16)); also writes xb ----------------
template<int P>
__global__ __launch_bounds__(192) void add_ln_kernel(
    const bf16* __restrict__ g, const float* __restrict__ xin,
    float* __restrict__ xout, bf16* __restrict__ xb,
    const float* __restrict__ gs, const float* __restrict__ gb) {
  __shared__ float red[3];
  int srow = blockIdx.x;
  int d = threadIdx.x * 4;
  size_t base = (size_t)srow * CD + d;
  float4 a = *(const float4*)&xin[base];
  #pragma unroll
  for (int p = 0; p < P; ++p) {
    ushort4 gg = *(const ushort4*)&g[p * SDC + base];
    a.x += bu2f(gg.x); a.y += bu2f(gg.y); a.z += bu2f(gg.z); a.w += bu2f(gg.w);
  }
  float sum = block_reduce_sum<3>(a.x + a.y + a.z + a.w, red);
  float mean = sum * (1.0f / CD);
  float cx = a.x - mean, cy = a.y - mean, cz = a.z - mean, cw = a.w - mean;
  float sq = block_reduce_sum<3>(cx * cx + cy * cy + cz * cz + cw * cw, red);
  float rstd = rsqrtf(sq * (1.0f / CD) + 1e-5f);
  float4 g4 = *(const float4*)&gs[d];
  float4 b4 = *(const float4*)&gb[d];
  float4 o;
  o.x = cx * rstd * g4.x + b4.x;
  o.y = cy * rstd * g4.y + b4.y;
  o.z = cz * rstd * g4.z + b4.z;
  o.w = cw * rstd * g4.w + b4.w;
  *(float4*)&xout[base] = o;
  ushort4 pk;
  pk.x = f2bu(o.x); pk.y = f2bu(o.y); pk.z = f2bu(o.z); pk.w = f2bu(o.w);
  *(ushort4*)&xb[base] = pk;
}

// ---------------- pooled = tanh(x[0] @ pool_W + pool_b) ----------------
__global__ __launch_bounds__(256) void pool_kernel(
    const float* __restrict__ x, const float* __restrict__ Wp,
    const float* __restrict__ bp, float* __restrict__ out) {
  __shared__ float xs[CD];
  __shared__ float red[4][64];
  int t = threadIdx.x;
  for (int i = t; i < CD; i += 256) xs[i] = x[i];
  __syncthreads();
  int n = blockIdx.x * 64 + (t & 63);
  int kp = t >> 6;
  float acc = 0.f;
  #pragma unroll 4
  for (int kk = kp * 192; kk < kp * 192 + 192; ++kk)
    acc = fmaf(xs[kk], Wp[(size_t)kk * CD + n], acc);
  red[kp][t & 63] = acc;
  __syncthreads();
  if (t < 64) {
    int nn = blockIdx.x * 64 + t;
    out[nn] = tanhf(red[0][t] + red[1][t] + red[2][t] + red[3][t] + bp[nn]);
  }
}

extern "C" void kernel_launch(void* const* d_in, const int* in_sizes, int n_in,
                              void* d_out, int out_size, void* d_ws, size_t ws_size,
                              hipStream_t stream) {
  const int*   ids   = (const int*)d_in[0];
  const int*   mask  = (const int*)d_in[1];
  const float* wemb  = (const float*)d_in[2];
  const float* pemb  = (const float*)d_in[3];
  const float* temb  = (const float*)d_in[4];
  const float* elns  = (const float*)d_in[5];
  const float* elnb  = (const float*)d_in[6];
  const float* Wqkv  = (const float*)d_in[7];
  const float* bqkv  = (const float*)d_in[8];
  const float* Wo    = (const float*)d_in[9];
  const float* bo    = (const float*)d_in[10];
  const float* ln1s  = (const float*)d_in[11];
  const float* ln1b  = (const float*)d_in[12];
  const float* W1    = (const float*)d_in[13];
  const float* b1    = (const float*)d_in[14];
  const float* W2    = (const float*)d_in[15];
  const float* b2    = (const float*)d_in[16];
  const float* ln2s  = (const float*)d_in[17];
  const float* ln2b  = (const float*)d_in[18];
  const float* poolW = (const float*)d_in[19];
  const float* poolb = (const float*)d_in[20];

  const size_t SD = SDC;
  const size_t SF = (size_t)CS * CF;

  char* w = (char*)d_ws;
  float* x    = (float*)w; w += SD * 4;
  bf16*  xb   = (bf16*)w;  w += SD * 2;
  bf16*  qkv  = (bf16*)w;  w += (size_t)CS * QKVN * 2;
  bf16*  vT   = (bf16*)w;  w += SD * 2;
  bf16*  ctxb = (bf16*)w;  w += SD * 2;
  bf16*  t1b  = (bf16*)w;  w += SF * 2;
  bf16*  t2   = (bf16*)w;  w += SD * 2 * 4;   // split-K bf16 partials
  bf16* WqkvT = (bf16*)w;  w += (size_t)CL * QKVN * CD * 2;
  bf16* WoT   = (bf16*)w;  w += (size_t)CL * CD * CD * 2;
  bf16* W1T   = (bf16*)w;  w += (size_t)CL * CF * CD * 2;
  bf16* W2T   = (bf16*)w;  w += (size_t)CL * CD * CF * 2;

  prep_kernel<<<6912 + CS, 256, 0, stream>>>(
      Wqkv, Wo, W1, W2, WqkvT, WoT, W1T, W2T,
      ids, mask, wemb, pemb, temb, elns, elnb, x, xb);

  for (int l = 0; l < CL; ++l) {
    gemm_mfma<0,1,1><<<dim3(QKVN/128, CS/64), 128, 0, stream>>>(
        xb, WqkvT + (size_t)l * QKVN * CD, bqkv + (size_t)l * 3 * CD, qkv, vT, CS, QKVN, CD);
    attn_mfma<<<dim3(CS/64, CH), 256, 0, stream>>>(qkv, vT, mask, ctxb);
    gemm_mfma<0,2,0><<<dim3(CD/128, CS/64, 2), 128, 0, stream>>>(
        ctxb, WoT + (size_t)l * CD * CD, bo + (size_t)l * CD, t2, nullptr, CS, CD, CD);
    add_ln_kernel<2><<<CS, 192, 0, stream>>>(t2, x, x, xb,
        ln1s + (size_t)l * CD, ln1b + (size_t)l * CD);
    gemm_mfma<1,1,0><<<dim3(CF/128, CS/64), 128, 0, stream>>>(
        xb, W1T + (size_t)l * CF * CD, b1 + (size_t)l * CF, t1b, nullptr, CS, CF, CD);
    gemm_mfma<0,2,0><<<dim3(CD/128, CS/64, 2), 128, 0, stream>>>(
        t1b, W2T + (size_t)l * CD * CF, b2 + (size_t)l * CD, t2, nullptr, CS, CD, CF);
    float* lastx = (l == CL - 1) ? (float*)d_out : x;
    add_ln_kernel<2><<<CS, 192, 0, stream>>>(t2, x, lastx, xb,
        ln2s + (size_t)l * CD, ln2b + (size_t)l * CD);
  }

  pool_kernel<<<12, 256, 0, stream>>>((float*)d_out, poolW, poolb, (float*)d_out + SD);
}

// Round 8
// 508.221 us; speedup vs baseline: 1.0816x; 1.0816x over previous
//
#include <hip/hip_runtime.h>
#include <hip/hip_bf16.h>
#include <math.h>
#include <stddef.h>
#include <stdint.h>

typedef __hip_bfloat16 bf16;
typedef short bf16x8 __attribute__((ext_vector_type(8)));
typedef float f32x4 __attribute__((ext_vector_type(4)));

#define CS 2048   // S
#define CD 768    // D
#define CH 12     // H
#define CDH 64    // DH
#define CF 3072   // F
#define CW 256    // W
#define CL 2      // L
#define QKVN 2304 // 3*D fused qkv width
#define SDC ((size_t)CS * CD)
#define EPS_LD 136  // epilogue LDS stride (bf16 elems)

// ---------------- async global->LDS, 16B per lane ----------------
__device__ __forceinline__ void gload_lds16(const bf16* g, bf16* l) {
  __builtin_amdgcn_global_load_lds(
      (const __attribute__((address_space(1))) void*)g,
      (__attribute__((address_space(3))) void*)l, 16, 0, 0);
}

__device__ __forceinline__ unsigned short f2bu(float v) {
  bf16 b = __float2bfloat16(v);
  return *(unsigned short*)&b;
}
__device__ __forceinline__ float bu2f(unsigned short u) {
  bf16 b = *(bf16*)&u;
  return __bfloat162float(b);
}

// ---------------- block reduction, NW waves ----------------
template<int NW>
__device__ __forceinline__ float block_reduce_sum(float v, float* buf) {
  #pragma unroll
  for (int off = 32; off > 0; off >>= 1) v += __shfl_down(v, off, 64);
  __syncthreads();
  if ((threadIdx.x & 63) == 0) buf[threadIdx.x >> 6] = v;
  __syncthreads();
  float s = buf[0];
  #pragma unroll
  for (int w = 1; w < NW; ++w) s += buf[w];
  return s;
}

// ---------------- fused: all-weights transpose->bf16  +  embedding gather + LN ----
__global__ __launch_bounds__(256) void prep_kernel(
    const float* __restrict__ Wqkv, const float* __restrict__ Wo,
    const float* __restrict__ W1, const float* __restrict__ W2,
    bf16* __restrict__ WqkvT, bf16* __restrict__ WoT,
    bf16* __restrict__ W1T, bf16* __restrict__ W2T,
    const int* __restrict__ ids, const int* __restrict__ mask,
    const float* __restrict__ wemb, const float* __restrict__ pemb,
    const float* __restrict__ temb, const float* __restrict__ gs,
    const float* __restrict__ gb, float* __restrict__ x, bf16* __restrict__ xb) {
  __shared__ float tile[64][33];
  __shared__ float red[4];
  int b = blockIdx.x;
  if (b < 6912) {
    // -------- weight transpose (fp32 K x N -> bf16 N x K) --------
    const float* src; bf16* dst; int K, N, t;
    if (b < 1728) {
      int mat = b / 288; t = b % 288; K = 768; N = 768;
      src = Wqkv + (size_t)mat * 768 * 768; dst = WqkvT + (size_t)mat * 768 * 768;
    } else if (b < 2304) {
      b -= 1728; int mat = b / 288; t = b % 288; K = 768; N = 768;
      src = Wo + (size_t)mat * 768 * 768; dst = WoT + (size_t)mat * 768 * 768;
    } else if (b < 4608) {
      b -= 2304; int mat = b / 1152; t = b % 1152; K = 768; N = 3072;
      src = W1 + (size_t)mat * 768 * 3072; dst = W1T + (size_t)mat * 768 * 3072;
    } else {
      b -= 4608; int mat = b / 1152; t = b % 1152; K = 3072; N = 768;
      src = W2 + (size_t)mat * 3072 * 768; dst = W2T + (size_t)mat * 3072 * 768;
    }
    int nt = N / 32;
    int bn = (t % nt) * 32, bk = (t / nt) * 64;
    int tx = threadIdx.x & 31, ty = (threadIdx.x >> 5);   // ty 0..7
    #pragma unroll
    for (int i = 0; i < 8; ++i)
      tile[ty + i * 8][tx] = src[(size_t)(bk + ty + i * 8) * N + bn + tx];
    __syncthreads();
    #pragma unroll
    for (int i = 0; i < 4; ++i) {
      int n = ty + i * 8;
      if (n < 32) {
        ushort2 pk;
        pk.x = f2bu(tile[2 * tx][n]);
        pk.y = f2bu(tile[2 * tx + 1][n]);
        *(ushort2*)&dst[(size_t)(bn + n) * K + bk + 2 * tx] = pk;
      }
    }
  } else {
    // -------- embedding + LN (vectorized: 192 lanes x float4) --------
    int srow = b - 6912;
    int t = threadIdx.x;
    float ps = 0.f;
    for (int i = t; i <= srow; i += 256) ps += (float)mask[i];
    float tot = block_reduce_sum<4>(ps, red);
    long long pid = (long long)((int)(tot + 0.5f) * mask[srow] + 1);
    long long id = ids[srow];
    float4 v = {0.f, 0.f, 0.f, 0.f};
    if (t < 192) {
      int d = t * 4;
      float4 a = *(const float4*)&wemb[id * CD + d];
      float4 p = *(const float4*)&pemb[pid * CD + d];
      float4 tm = *(const float4*)&temb[d];
      v.x = a.x + p.x + tm.x; v.y = a.y + p.y + tm.y;
      v.z = a.z + p.z + tm.z; v.w = a.w + p.w + tm.w;
    }
    float sum = block_reduce_sum<4>(v.x + v.y + v.z + v.w, red);
    float mean = sum * (1.0f / CD);
    float cx = v.x - mean, cy = v.y - mean, cz = v.z - mean, cw = v.w - mean;
    float sqv = (t < 192) ? (cx * cx + cy * cy + cz * cz + cw * cw) : 0.f;
    float sq = block_reduce_sum<4>(sqv, red);
    float rstd = rsqrtf(sq * (1.0f / CD) + 1e-5f);
    if (t < 192) {
      int d = t * 4;
      float4 g4 = *(const float4*)&gs[d];
      float4 b4 = *(const float4*)&gb[d];
      float4 o;
      o.x = cx * rstd * g4.x + b4.x;
      o.y = cy * rstd * g4.y + b4.y;
      o.z = cz * rstd * g4.z + b4.z;
      o.w = cw * rstd * g4.w + b4.w;
      *(float4*)&x[(size_t)srow * CD + d] = o;
      ushort4 pk;
      pk.x = f2bu(o.x); pk.y = f2bu(o.y); pk.z = f2bu(o.z); pk.w = f2bu(o.w);
      *(ushort4*)&xb[(size_t)srow * CD + d] = pk;
    }
  }
}

// ---------------- MFMA GEMM: BM x 128 tile, BM/32 waves, BK=64, 2-phase dbuf ----
// Proven 2-phase schedule (round 5): STAGE(next) before compute(cur), single
// vmcnt(0)+s_barrier per tile. BM=128 (4 waves): MFMA phase ~2x longer -> the
// one-tile prefetch distance fully covers L2 latency AND staging bytes/FLOP
// halve (m103 tile ladder). BM=64 (2 waves) kept for N=768 GEMMs (grid size).
template<int BM, int GELU, int SPLITS, int TRANS>
__device__ __forceinline__ void gemm_body(
    const bf16* __restrict__ A, const bf16* __restrict__ Bt,
    const float* __restrict__ bias, bf16* __restrict__ Cout,
    bf16* __restrict__ vTout, int M, int N, int Ktot, char* smem,
    int bx, int by) {
  constexpr int NW = BM / 32;            // waves per block
  constexpr int A_OPS = BM / 8;          // 64-lane staging ops for A tile
  constexpr int OPW = (A_OPS + 16) / NW; // staging ops per wave
  constexpr int AS_STRIDE = BM * 64;     // elems per A buffer
  bf16* As = (bf16*)smem;
  bf16* Bs = (bf16*)(smem + AS_STRIDE * 2 * 2);  // after 2 A buffers
  bf16* eps = (bf16*)smem;                       // epilogue tile, aliases staging
  const int tid = threadIdx.x;
  const int wave = tid >> 6, lane = tid & 63;
  const int m0 = by * BM, n0 = bx * 128;
  const int wm = (BM == 64) ? 0 : (wave & 1) * 64;
  const int wn = (BM == 64) ? wave * 64 : (wave >> 1) * 64;
  const int quad = lane >> 4, rsel = lane & 15;
  const int rx = rsel & 7;
  const int r_in = lane >> 3;          // staging row within op (0..7)
  const int chunk = lane & 7;          // staging LDS chunk c'
  const int gchunk = chunk ^ r_in;     // global chunk to load
  const int Klen = Ktot / SPLITS;
  const int koff = (SPLITS > 1) ? blockIdx.z * Klen : 0;
  const int nt = Klen / 64;

  f32x4 acc[4][4] = {};

  auto STAGE = [&](int buf, int t) {
    const int kk = koff + t * 64;
    bf16* Asb = As + buf * AS_STRIDE;
    bf16* Bsb = Bs + buf * 8192;
    #pragma unroll
    for (int i = 0; i < OPW; ++i) {
      int op = wave * OPW + i;
      if (op < A_OPS) {
        int row = op * 8 + r_in;
        gload_lds16(A + (size_t)(m0 + row) * Ktot + kk + gchunk * 8, &Asb[op * 512]);
      } else {
        int row = (op - A_OPS) * 8 + r_in;
        gload_lds16(Bt + (size_t)(n0 + row) * Ktot + kk + gchunk * 8, &Bsb[(op - A_OPS) * 512]);
      }
    }
  };

  // prologue: stage tile 0, drain, sync
  STAGE(0, 0);
  __asm__ volatile("s_waitcnt vmcnt(0)" ::: "memory");
  __builtin_amdgcn_s_barrier();
  __builtin_amdgcn_sched_barrier(0);

  int cur = 0;
  for (int t = 0; t < nt; ++t) {
    if (t + 1 < nt) STAGE(cur ^ 1, t + 1);   // prefetch next tile (async)
    __builtin_amdgcn_sched_barrier(0);       // pin issue before ds_reads
    const bf16* Asb = As + cur * AS_STRIDE;
    const bf16* Bsb = Bs + cur * 8192;
    #pragma unroll
    for (int kh = 0; kh < 2; ++kh) {
      bf16x8 af[4], bfr[4];
      int cq = ((kh << 2) | quad);
      #pragma unroll
      for (int i = 0; i < 4; ++i)
        af[i] = *(const bf16x8*)&Asb[(wm + i * 16 + rsel) * 64 + (cq ^ rx) * 8];
      #pragma unroll
      for (int j = 0; j < 4; ++j)
        bfr[j] = *(const bf16x8*)&Bsb[(wn + j * 16 + rsel) * 64 + (cq ^ rx) * 8];
      #pragma unroll
      for (int i = 0; i < 4; ++i)
        #pragma unroll
        for (int j = 0; j < 4; ++j) {
          if (TRANS)
            acc[i][j] = __builtin_amdgcn_mfma_f32_16x16x32_bf16(af[i], bfr[j], acc[i][j], 0, 0, 0);
          else
            acc[i][j] = __builtin_amdgcn_mfma_f32_16x16x32_bf16(bfr[j], af[i], acc[i][j], 0, 0, 0);
        }
    }
    // next buffer fully landed + all reads of cur complete before re-stage
    __asm__ volatile("s_waitcnt vmcnt(0)" ::: "memory");
    __builtin_amdgcn_s_barrier();
    __builtin_amdgcn_sched_barrier(0);
    cur ^= 1;
  }

  if (!TRANS) {
    // value(i,j,r) = C[m0+wm+i*16+rsel][n0+wn+j*16+quad*4+r]
    #pragma unroll
    for (int j = 0; j < 4; ++j) {
      int cb = wn + j * 16 + quad * 4;
      float4 bv = {0.f, 0.f, 0.f, 0.f};
      if (SPLITS == 1 || blockIdx.z == 0) bv = *(const float4*)&bias[n0 + cb];
      #pragma unroll
      for (int i = 0; i < 4; ++i) {
        float v0 = acc[i][j][0] + bv.x;
        float v1 = acc[i][j][1] + bv.y;
        float v2 = acc[i][j][2] + bv.z;
        float v3 = acc[i][j][3] + bv.w;
        if (GELU) {
          v0 = 0.5f * v0 * (1.0f + erff(v0 * 0.70710678118654752f));
          v1 = 0.5f * v1 * (1.0f + erff(v1 * 0.70710678118654752f));
          v2 = 0.5f * v2 * (1.0f + erff(v2 * 0.70710678118654752f));
          v3 = 0.5f * v3 * (1.0f + erff(v3 * 0.70710678118654752f));
        }
        ushort4 pk;
        pk.x = f2bu(v0); pk.y = f2bu(v1); pk.z = f2bu(v2); pk.w = f2bu(v3);
        *(ushort4*)&eps[(wm + i * 16 + rsel) * EPS_LD + cb] = pk;
      }
    }
    __syncthreads();
    const size_t zb = (SPLITS > 1) ? (size_t)blockIdx.z * M * N : 0;
    #pragma unroll
    for (int it = 0; it < 8; ++it) {
      int row = it * (BM / 8) + (tid >> 4);
      int c = tid & 15;
      bf16x8 v = *(const bf16x8*)&eps[row * EPS_LD + c * 8];
      *(bf16x8*)&Cout[zb + (size_t)(m0 + row) * N + n0 + c * 8] = v;
    }
  } else {
    // value(i,j,r) = C[m0+wm+i*16+quad*4+r][n0+wn+j*16+rsel]; LDS tile is [n][m]
    #pragma unroll
    for (int j = 0; j < 4; ++j) {
      float bv = bias[n0 + wn + j * 16 + rsel];
      #pragma unroll
      for (int i = 0; i < 4; ++i) {
        ushort4 pk;
        pk.x = f2bu(acc[i][j][0] + bv);
        pk.y = f2bu(acc[i][j][1] + bv);
        pk.z = f2bu(acc[i][j][2] + bv);
        pk.w = f2bu(acc[i][j][3] + bv);
        *(ushort4*)&eps[(wn + j * 16 + rsel) * EPS_LD + wm + i * 16 + quad * 4] = pk;
      }
    }
    __syncthreads();
    #pragma unroll
    for (int it = 0; it < 8; ++it) {
      int row, c;
      if (BM == 64) { row = it * 16 + (tid >> 3); c = tid & 7; }
      else          { row = it * 16 + (tid >> 4); c = tid & 15; }
      bf16x8 v = *(const bf16x8*)&eps[row * EPS_LD + c * 8];
      *(bf16x8*)&vTout[(size_t)(n0 - 1536 + row) * CS + m0 + c * 8] = v;
    }
  }
}

template<int BM, int GELU, int SPLITS, int VTFUSE>
__global__ __launch_bounds__(BM * 2, BM == 64 ? 3 : 2) void gemm_mfma(
    const bf16* __restrict__ A, const bf16* __restrict__ Bt,
    const float* __restrict__ bias, bf16* __restrict__ Cout,
    bf16* __restrict__ vTout, int M, int N, int Ktot) {
  // dbuf staging: BM=64 -> 48KB; BM=128 -> 64KB. eps aliases (max 34816B).
  __shared__ __align__(16) char smem[BM * 256 + 32768];
  int nx = gridDim.x, ny = gridDim.y;
  int nwg = nx * ny;
  int orig = blockIdx.x + blockIdx.y * nx;
  int bx, by;
  if (nwg & 7) { bx = blockIdx.x; by = blockIdx.y; }
  else {
    int q8 = nwg >> 3;
    int nid = (orig & 7) * q8 + (orig >> 3);
    bx = nid / ny; by = nid - bx * ny;
  }
  if (VTFUSE && bx * 128 >= 1536)
    gemm_body<BM, 0, 1, 1>(A, Bt, bias, Cout, vTout, M, N, Ktot, smem, bx, by);
  else
    gemm_body<BM, GELU, SPLITS, 0>(A, Bt, bias, Cout, vTout, M, N, Ktot, smem, bx, by);
}

// ---------------- MFMA flash attention v2 (banded), LDS-staged K/V ----------------
__global__ __launch_bounds__(256) void attn_mfma(
    const bf16* __restrict__ qkv, const bf16* __restrict__ vT,
    const int* __restrict__ mask, bf16* __restrict__ ctx) {
  __shared__ __align__(16) bf16 Ks[64 * 64];
  __shared__ __align__(16) bf16 Vs[64 * 64];
  __shared__ __align__(16) bf16 Ps[4][16][72];
  const int h = blockIdx.y;
  const int q0 = blockIdx.x * 64;
  const int tid = threadIdx.x;
  const int wv = tid >> 6, lane = tid & 63;
  const int quad = lane >> 4, rsel = lane & 15;
  const int rx = rsel & 7;
  const int qw = q0 + wv * 16;
  const int r_in = lane >> 3, chunk = lane & 7, gchunk = chunk ^ r_in;

  const bf16* qp = &qkv[(size_t)(qw + rsel) * QKVN + h * CDH + quad * 8];
  bf16x8 qf0 = *(const bf16x8*)qp;
  bf16x8 qf1 = *(const bf16x8*)(qp + 32);

  float mi[4], li[4];
  f32x4 o[4] = {};
  #pragma unroll
  for (int r = 0; r < 4; ++r) { mi[r] = -1e30f; li[r] = 0.f; }

  #pragma unroll 1
  for (int kt = 0; kt < 9; ++kt) {
    int kbase = q0 - CW + kt * 64;
    bool tile_in = (kbase + 63 >= 0) && (kbase < CS);
    if (tile_in) {
      #pragma unroll
      for (int i = 0; i < 4; ++i) {
        int op = wv * 4 + i;     // 0..15: 8 K ops + 8 V ops
        if (op < 8) {
          int krow = min(max(kbase + op * 8 + r_in, 0), CS - 1);
          gload_lds16(&qkv[(size_t)krow * QKVN + 768 + h * CDH + gchunk * 8], &Ks[op * 512]);
        } else {
          int vop = op - 8;
          int kc = min(max(kbase + gchunk * 8, 0), CS - 8);
          gload_lds16(&vT[(size_t)(h * CDH + vop * 8 + r_in) * CS + kc], &Vs[vop * 512]);
        }
      }
    }
    __syncthreads();
    bool active = tile_in && (kbase + 63 >= qw - CW) && (kbase <= qw + 15 + CW);
    if (active) {
      f32x4 sc[4];
      #pragma unroll
      for (int nt = 0; nt < 4; ++nt) {
        const bf16* kp = &Ks[(nt * 16 + rsel) * 64];
        bf16x8 kf0 = *(const bf16x8*)(kp + (quad ^ rx) * 8);
        bf16x8 kf1 = *(const bf16x8*)(kp + ((quad + 4) ^ rx) * 8);
        f32x4 z = {};
        __builtin_amdgcn_s_setprio(1);
        z = __builtin_amdgcn_mfma_f32_16x16x32_bf16(qf0, kf0, z, 0, 0, 0);
        z = __builtin_amdgcn_mfma_f32_16x16x32_bf16(qf1, kf1, z, 0, 0, 0);
        __builtin_amdgcn_s_setprio(0);
        sc[nt] = z;
      }
      float mx[4] = {-1e30f, -1e30f, -1e30f, -1e30f};
      #pragma unroll
      for (int nt = 0; nt < 4; ++nt) {
        int pp = kbase + nt * 16 + rsel;
        int ppc = min(max(pp, 0), CS - 1);
        bool kvld = (pp >= 0) && (pp < CS) && (mask[ppc] != 0);
        #pragma unroll
        for (int r = 0; r < 4; ++r) {
          int qr = qw + quad * 4 + r;
          float s = sc[nt][r] * 0.125f;
          bool band = (pp >= qr - CW) && (pp <= qr + CW);
          s = (kvld && band) ? s : -1e9f;
          sc[nt][r] = s;
          mx[r] = fmaxf(mx[r], s);
        }
      }
      #pragma unroll
      for (int r = 0; r < 4; ++r) {
        #pragma unroll
        for (int off = 1; off < 16; off <<= 1)
          mx[r] = fmaxf(mx[r], __shfl_xor(mx[r], off, 64));
      }
      float al[4], rs[4] = {};
      #pragma unroll
      for (int r = 0; r < 4; ++r) {
        float mn = fmaxf(mi[r], mx[r]);
        al[r] = __expf(mi[r] - mn);
        mi[r] = mn;
      }
      #pragma unroll
      for (int nt = 0; nt < 4; ++nt)
        #pragma unroll
        for (int r = 0; r < 4; ++r) {
          float p = __expf(sc[nt][r] - mi[r]);
          sc[nt][r] = p;
          rs[r] += p;
        }
      #pragma unroll
      for (int r = 0; r < 4; ++r) {
        #pragma unroll
        for (int off = 1; off < 16; off <<= 1)
          rs[r] += __shfl_xor(rs[r], off, 64);
        li[r] = li[r] * al[r] + rs[r];
      }
      #pragma unroll
      for (int d = 0; d < 4; ++d)
        #pragma unroll
        for (int r = 0; r < 4; ++r) o[d][r] *= al[r];
      #pragma unroll
      for (int nt = 0; nt < 4; ++nt)
        #pragma unroll
        for (int r = 0; r < 4; ++r)
          Ps[wv][quad * 4 + r][nt * 16 + rsel] = __float2bfloat16(sc[nt][r]);
      __asm__ volatile("s_waitcnt lgkmcnt(0)" ::: "memory");
      __builtin_amdgcn_sched_barrier(0);
      bf16x8 pf0 = *(const bf16x8*)&Ps[wv][rsel][quad * 8];
      bf16x8 pf1 = *(const bf16x8*)&Ps[wv][rsel][32 + quad * 8];
      #pragma unroll
      for (int d = 0; d < 4; ++d) {
        const bf16* vr = &Vs[(d * 16 + rsel) * 64];
        bf16x8 vf0 = *(const bf16x8*)(vr + (quad ^ rx) * 8);
        bf16x8 vf1 = *(const bf16x8*)(vr + ((quad + 4) ^ rx) * 8);
        __builtin_amdgcn_s_setprio(1);
        o[d] = __builtin_amdgcn_mfma_f32_16x16x32_bf16(pf0, vf0, o[d], 0, 0, 0);
        o[d] = __builtin_amdgcn_mfma_f32_16x16x32_bf16(pf1, vf1, o[d], 0, 0, 0);
        __builtin_amdgcn_s_setprio(0);
      }
    }
    __syncthreads();
  }

  float inv[4];
  #pragma unroll
  for (int r = 0; r < 4; ++r) inv[r] = 1.0f / li[r];
  #pragma unroll
  for (int d = 0; d < 4; ++d)
    #pragma unroll
    for (int r = 0; r < 4; ++r)
      Ps[wv][quad * 4 + r][d * 16 + rsel] = __float2bfloat16(o[d][r] * inv[r]);
  __asm__ volatile("s_waitcnt lgkmcnt(0)" ::: "memory");
  __builtin_amdgcn_sched_barrier(0);
  #pragma unroll
  for (int it = 0; it < 2; ++it) {
    int row = it * 8 + (lane >> 3);
    bf16x8 vv = *(const bf16x8*)&Ps[wv][row][(lane & 7) * 8];
    *(bf16x8*)&ctx[(size_t)(qw + row) * CD + h * CDH + (lane & 7) * 8] = vv;
  }
}

// ---------------- xout = LN(xin + sum_p g[p](bf16)); also writes xb ----------------
template<int P>
__global__ __launch_bounds__(192) void add_ln_kernel(
    const bf16* __restrict__ g, const float* __restrict__ xin,
    float* __restrict__ xout, bf16* __restrict__ xb,
    const float* __restrict__ gs, const float* __restrict__ gb) {
  __shared__ float red[3];
  int srow = blockIdx.x;
  int d = threadIdx.x * 4;
  size_t base = (size_t)srow * CD + d;
  float4 a = *(const float4*)&xin[base];
  #pragma unroll
  for (int p = 0; p < P; ++p) {
    ushort4 gg = *(const ushort4*)&g[p * SDC + base];
    a.x += bu2f(gg.x); a.y += bu2f(gg.y); a.z += bu2f(gg.z); a.w += bu2f(gg.w);
  }
  float sum = block_reduce_sum<3>(a.x + a.y + a.z + a.w, red);
  float mean = sum * (1.0f / CD);
  float cx = a.x - mean, cy = a.y - mean, cz = a.z - mean, cw = a.w - mean;
  float sq = block_reduce_sum<3>(cx * cx + cy * cy + cz * cz + cw * cw, red);
  float rstd = rsqrtf(sq * (1.0f / CD) + 1e-5f);
  float4 g4 = *(const float4*)&gs[d];
  float4 b4 = *(const float4*)&gb[d];
  float4 o;
  o.x = cx * rstd * g4.x + b4.x;
  o.y = cy * rstd * g4.y + b4.y;
  o.z = cz * rstd * g4.z + b4.z;
  o.w = cw * rstd * g4.w + b4.w;
  *(float4*)&xout[base] = o;
  ushort4 pk;
  pk.x = f2bu(o.x); pk.y = f2bu(o.y); pk.z = f2bu(o.z); pk.w = f2bu(o.w);
  *(ushort4*)&xb[base] = pk;
}

// ---------------- pooled = tanh(x[0] @ pool_W + pool_b) ----------------
__global__ __launch_bounds__(256) void pool_kernel(
    const float* __restrict__ x, const float* __restrict__ Wp,
    const float* __restrict__ bp, float* __restrict__ out) {
  __shared__ float xs[CD];
  __shared__ float red[4][64];
  int t = threadIdx.x;
  for (int i = t; i < CD; i += 256) xs[i] = x[i];
  __syncthreads();
  int n = blockIdx.x * 64 + (t & 63);
  int kp = t >> 6;
  float acc = 0.f;
  #pragma unroll 4
  for (int kk = kp * 192; kk < kp * 192 + 192; ++kk)
    acc = fmaf(xs[kk], Wp[(size_t)kk * CD + n], acc);
  red[kp][t & 63] = acc;
  __syncthreads();
  if (t < 64) {
    int nn = blockIdx.x * 64 + t;
    out[nn] = tanhf(red[0][t] + red[1][t] + red[2][t] + red[3][t] + bp[nn]);
  }
}

extern "C" void kernel_launch(void* const* d_in, const int* in_sizes, int n_in,
                              void* d_out, int out_size, void* d_ws, size_t ws_size,
                              hipStream_t stream) {
  const int*   ids   = (const int*)d_in[0];
  const int*   mask  = (const int*)d_in[1];
  const float* wemb  = (const float*)d_in[2];
  const float* pemb  = (const float*)d_in[3];
  const float* temb  = (const float*)d_in[4];
  const float* elns  = (const float*)d_in[5];
  const float* elnb  = (const float*)d_in[6];
  const float* Wqkv  = (const float*)d_in[7];
  const float* bqkv  = (const float*)d_in[8];
  const float* Wo    = (const float*)d_in[9];
  const float* bo    = (const float*)d_in[10];
  const float* ln1s  = (const float*)d_in[11];
  const float* ln1b  = (const float*)d_in[12];
  const float* W1    = (const float*)d_in[13];
  const float* b1    = (const float*)d_in[14];
  const float* W2    = (const float*)d_in[15];
  const float* b2    = (const float*)d_in[16];
  const float* ln2s  = (const float*)d_in[17];
  const float* ln2b  = (const float*)d_in[18];
  const float* poolW = (const float*)d_in[19];
  const float* poolb = (const float*)d_in[20];

  const size_t SD = SDC;
  const size_t SF = (size_t)CS * CF;

  char* w = (char*)d_ws;
  float* x    = (float*)w; w += SD * 4;
  bf16*  xb   = (bf16*)w;  w += SD * 2;
  bf16*  qkv  = (bf16*)w;  w += (size_t)CS * QKVN * 2;
  bf16*  vT   = (bf16*)w;  w += SD * 2;
  bf16*  ctxb = (bf16*)w;  w += SD * 2;
  bf16*  t1b  = (bf16*)w;  w += SF * 2;
  bf16*  t2   = (bf16*)w;  w += SD * 2 * 4;   // split-K bf16 partials
  bf16* WqkvT = (bf16*)w;  w += (size_t)CL * QKVN * CD * 2;
  bf16* WoT   = (bf16*)w;  w += (size_t)CL * CD * CD * 2;
  bf16* W1T   = (bf16*)w;  w += (size_t)CL * CF * CD * 2;
  bf16* W2T   = (bf16*)w;  w += (size_t)CL * CD * CF * 2;

  prep_kernel<<<6912 + CS, 256, 0, stream>>>(
      Wqkv, Wo, W1, W2, WqkvT, WoT, W1T, W2T,
      ids, mask, wemb, pemb, temb, elns, elnb, x, xb);

  for (int l = 0; l < CL; ++l) {
    gemm_mfma<128,0,1,1><<<dim3(QKVN/128, CS/128), 256, 0, stream>>>(
        xb, WqkvT + (size_t)l * QKVN * CD, bqkv + (size_t)l * 3 * CD, qkv, vT, CS, QKVN, CD);
    attn_mfma<<<dim3(CS/64, CH), 256, 0, stream>>>(qkv, vT, mask, ctxb);
    gemm_mfma<64,0,2,0><<<dim3(CD/128, CS/64, 2), 128, 0, stream>>>(
        ctxb, WoT + (size_t)l * CD * CD, bo + (size_t)l * CD, t2, nullptr, CS, CD, CD);
    add_ln_kernel<2><<<CS, 192, 0, stream>>>(t2, x, x, xb,
        ln1s + (size_t)l * CD, ln1b + (size_t)l * CD);
    gemm_mfma<128,1,1,0><<<dim3(CF/128, CS/128), 256, 0, stream>>>(
        xb, W1T + (size_t)l * CF * CD, b1 + (size_t)l * CF, t1b, nullptr, CS, CF, CD);
    gemm_mfma<64,0,2,0><<<dim3(CD/128, CS/64, 2), 128, 0, stream>>>(
        t1b, W2T + (size_t)l * CD * CF, b2 + (size_t)l * CD, t2, nullptr, CS, CD, CF);
    float* lastx = (l == CL - 1) ? (float*)d_out : x;
    add_ln_kernel<2><<<CS, 192, 0, stream>>>(t2, x, lastx, xb,
        ln2s + (size_t)l * CD, ln2b + (size_t)l * CD);
  }

  pool_kernel<<<12, 256, 0, stream>>>((float*)d_out, poolW, poolb, (float*)d_out + SD);
}

// Round 11
// 506.625 us; speedup vs baseline: 1.0850x; 1.0031x over previous
//
#include <hip/hip_runtime.h>
#include <hip/hip_bf16.h>
#include <math.h>
#include <stddef.h>
#include <stdint.h>

typedef __hip_bfloat16 bf16;
typedef short bf16x8 __attribute__((ext_vector_type(8)));
typedef float f32x4 __attribute__((ext_vector_type(4)));

#define CS 2048   // S
#define CD 768    // D
#define CH 12     // H
#define CDH 64    // DH
#define CF 3072   // F
#define CW 256    // W
#define CL 2      // L
#define QKVN 2304 // 3*D fused qkv width
#define SDC ((size_t)CS * CD)
#define EPS_LD 136  // epilogue LDS stride (bf16 elems)

// ---------------- async global->LDS, 16B per lane ----------------
__device__ __forceinline__ void gload_lds16(const bf16* g, bf16* l) {
  __builtin_amdgcn_global_load_lds(
      (const __attribute__((address_space(1))) void*)g,
      (__attribute__((address_space(3))) void*)l, 16, 0, 0);
}

__device__ __forceinline__ unsigned short f2bu(float v) {
  bf16 b = __float2bfloat16(v);
  return *(unsigned short*)&b;
}
__device__ __forceinline__ float bu2f(unsigned short u) {
  bf16 b = *(bf16*)&u;
  return __bfloat162float(b);
}

// ---------------- block reduction, NW waves ----------------
template<int NW>
__device__ __forceinline__ float block_reduce_sum(float v, float* buf) {
  #pragma unroll
  for (int off = 32; off > 0; off >>= 1) v += __shfl_down(v, off, 64);
  __syncthreads();
  if ((threadIdx.x & 63) == 0) buf[threadIdx.x >> 6] = v;
  __syncthreads();
  float s = buf[0];
  #pragma unroll
  for (int w = 1; w < NW; ++w) s += buf[w];
  return s;
}

// ---------------- fused: all-weights transpose->bf16  +  embedding gather + LN ----
__global__ __launch_bounds__(256) void prep_kernel(
    const float* __restrict__ Wqkv, const float* __restrict__ Wo,
    const float* __restrict__ W1, const float* __restrict__ W2,
    bf16* __restrict__ WqkvT, bf16* __restrict__ WoT,
    bf16* __restrict__ W1T, bf16* __restrict__ W2T,
    const int* __restrict__ ids, const int* __restrict__ mask,
    const float* __restrict__ wemb, const float* __restrict__ pemb,
    const float* __restrict__ temb, const float* __restrict__ gs,
    const float* __restrict__ gb, float* __restrict__ x, bf16* __restrict__ xb) {
  __shared__ float tile[64][33];
  __shared__ float red[4];
  int b = blockIdx.x;
  if (b < 6912) {
    // -------- weight transpose (fp32 K x N -> bf16 N x K) --------
    const float* src; bf16* dst; int K, N, t;
    if (b < 1728) {
      int mat = b / 288; t = b % 288; K = 768; N = 768;
      src = Wqkv + (size_t)mat * 768 * 768; dst = WqkvT + (size_t)mat * 768 * 768;
    } else if (b < 2304) {
      b -= 1728; int mat = b / 288; t = b % 288; K = 768; N = 768;
      src = Wo + (size_t)mat * 768 * 768; dst = WoT + (size_t)mat * 768 * 768;
    } else if (b < 4608) {
      b -= 2304; int mat = b / 1152; t = b % 1152; K = 768; N = 3072;
      src = W1 + (size_t)mat * 768 * 3072; dst = W1T + (size_t)mat * 768 * 3072;
    } else {
      b -= 4608; int mat = b / 1152; t = b % 1152; K = 3072; N = 768;
      src = W2 + (size_t)mat * 3072 * 768; dst = W2T + (size_t)mat * 3072 * 768;
    }
    int nt = N / 32;
    int bn = (t % nt) * 32, bk = (t / nt) * 64;
    int tx = threadIdx.x & 31, ty = (threadIdx.x >> 5);   // ty 0..7
    #pragma unroll
    for (int i = 0; i < 8; ++i)
      tile[ty + i * 8][tx] = src[(size_t)(bk + ty + i * 8) * N + bn + tx];
    __syncthreads();
    #pragma unroll
    for (int i = 0; i < 4; ++i) {
      int n = ty + i * 8;
      if (n < 32) {
        ushort2 pk;
        pk.x = f2bu(tile[2 * tx][n]);
        pk.y = f2bu(tile[2 * tx + 1][n]);
        *(ushort2*)&dst[(size_t)(bn + n) * K + bk + 2 * tx] = pk;
      }
    }
  } else {
    // -------- embedding + LN (vectorized: 192 lanes x float4) --------
    int srow = b - 6912;
    int t = threadIdx.x;
    float ps = 0.f;
    for (int i = t; i <= srow; i += 256) ps += (float)mask[i];
    float tot = block_reduce_sum<4>(ps, red);
    long long pid = (long long)((int)(tot + 0.5f) * mask[srow] + 1);
    long long id = ids[srow];
    float4 v = {0.f, 0.f, 0.f, 0.f};
    if (t < 192) {
      int d = t * 4;
      float4 a = *(const float4*)&wemb[id * CD + d];
      float4 p = *(const float4*)&pemb[pid * CD + d];
      float4 tm = *(const float4*)&temb[d];
      v.x = a.x + p.x + tm.x; v.y = a.y + p.y + tm.y;
      v.z = a.z + p.z + tm.z; v.w = a.w + p.w + tm.w;
    }
    float sum = block_reduce_sum<4>(v.x + v.y + v.z + v.w, red);
    float mean = sum * (1.0f / CD);
    float cx = v.x - mean, cy = v.y - mean, cz = v.z - mean, cw = v.w - mean;
    float sqv = (t < 192) ? (cx * cx + cy * cy + cz * cz + cw * cw) : 0.f;
    float sq = block_reduce_sum<4>(sqv, red);
    float rstd = rsqrtf(sq * (1.0f / CD) + 1e-5f);
    if (t < 192) {
      int d = t * 4;
      float4 g4 = *(const float4*)&gs[d];
      float4 b4 = *(const float4*)&gb[d];
      float4 o;
      o.x = cx * rstd * g4.x + b4.x;
      o.y = cy * rstd * g4.y + b4.y;
      o.z = cz * rstd * g4.z + b4.z;
      o.w = cw * rstd * g4.w + b4.w;
      *(float4*)&x[(size_t)srow * CD + d] = o;
      ushort4 pk;
      pk.x = f2bu(o.x); pk.y = f2bu(o.y); pk.z = f2bu(o.z); pk.w = f2bu(o.w);
      *(ushort4*)&xb[(size_t)srow * CD + d] = pk;
    }
  }
}

// ---------------- MFMA GEMM: BM x 128 tile, BM/32 waves, BK=64, 2-phase dbuf ----
template<int BM, int GELU, int SPLITS, int TRANS>
__device__ __forceinline__ void gemm_body(
    const bf16* __restrict__ A, const bf16* __restrict__ Bt,
    const float* __restrict__ bias, bf16* __restrict__ Cout,
    bf16* __restrict__ vTout, int M, int N, int Ktot, char* smem,
    int bx, int by) {
  constexpr int NW = BM / 32;            // waves per block
  constexpr int A_OPS = BM / 8;          // 64-lane staging ops for A tile
  constexpr int OPW = (A_OPS + 16) / NW; // staging ops per wave
  constexpr int AS_STRIDE = BM * 64;     // elems per A buffer
  bf16* As = (bf16*)smem;
  bf16* Bs = (bf16*)(smem + AS_STRIDE * 2 * 2);  // after 2 A buffers
  bf16* eps = (bf16*)smem;                       // epilogue tile, aliases staging
  const int tid = threadIdx.x;
  const int wave = tid >> 6, lane = tid & 63;
  const int m0 = by * BM, n0 = bx * 128;
  const int wm = (BM == 64) ? 0 : (wave & 1) * 64;
  const int wn = (BM == 64) ? wave * 64 : (wave >> 1) * 64;
  const int quad = lane >> 4, rsel = lane & 15;
  const int rx = rsel & 7;
  const int r_in = lane >> 3;          // staging row within op (0..7)
  const int chunk = lane & 7;          // staging LDS chunk c'
  const int gchunk = chunk ^ r_in;     // global chunk to load
  const int Klen = Ktot / SPLITS;
  const int koff = (SPLITS > 1) ? blockIdx.z * Klen : 0;
  const int nt = Klen / 64;

  f32x4 acc[4][4] = {};

  auto STAGE = [&](int buf, int t) {
    const int kk = koff + t * 64;
    bf16* Asb = As + buf * AS_STRIDE;
    bf16* Bsb = Bs + buf * 8192;
    #pragma unroll
    for (int i = 0; i < OPW; ++i) {
      int op = wave * OPW + i;
      if (op < A_OPS) {
        int row = op * 8 + r_in;
        gload_lds16(A + (size_t)(m0 + row) * Ktot + kk + gchunk * 8, &Asb[op * 512]);
      } else {
        int row = (op - A_OPS) * 8 + r_in;
        gload_lds16(Bt + (size_t)(n0 + row) * Ktot + kk + gchunk * 8, &Bsb[(op - A_OPS) * 512]);
      }
    }
  };

  // prologue: stage tile 0, drain, sync
  STAGE(0, 0);
  __asm__ volatile("s_waitcnt vmcnt(0)" ::: "memory");
  __builtin_amdgcn_s_barrier();
  __builtin_amdgcn_sched_barrier(0);

  int cur = 0;
  for (int t = 0; t < nt; ++t) {
    if (t + 1 < nt) STAGE(cur ^ 1, t + 1);   // prefetch next tile (async)
    __builtin_amdgcn_sched_barrier(0);       // pin issue before ds_reads
    const bf16* Asb = As + cur * AS_STRIDE;
    const bf16* Bsb = Bs + cur * 8192;
    #pragma unroll
    for (int kh = 0; kh < 2; ++kh) {
      bf16x8 af[4], bfr[4];
      int cq = ((kh << 2) | quad);
      #pragma unroll
      for (int i = 0; i < 4; ++i)
        af[i] = *(const bf16x8*)&Asb[(wm + i * 16 + rsel) * 64 + (cq ^ rx) * 8];
      #pragma unroll
      for (int j = 0; j < 4; ++j)
        bfr[j] = *(const bf16x8*)&Bsb[(wn + j * 16 + rsel) * 64 + (cq ^ rx) * 8];
      #pragma unroll
      for (int i = 0; i < 4; ++i)
        #pragma unroll
        for (int j = 0; j < 4; ++j) {
          if (TRANS)
            acc[i][j] = __builtin_amdgcn_mfma_f32_16x16x32_bf16(af[i], bfr[j], acc[i][j], 0, 0, 0);
          else
            acc[i][j] = __builtin_amdgcn_mfma_f32_16x16x32_bf16(bfr[j], af[i], acc[i][j], 0, 0, 0);
        }
    }
    // next buffer fully landed + all reads of cur complete before re-stage
    __asm__ volatile("s_waitcnt vmcnt(0)" ::: "memory");
    __builtin_amdgcn_s_barrier();
    __builtin_amdgcn_sched_barrier(0);
    cur ^= 1;
  }

  if (!TRANS) {
    // value(i,j,r) = C[m0+wm+i*16+rsel][n0+wn+j*16+quad*4+r]
    #pragma unroll
    for (int j = 0; j < 4; ++j) {
      int cb = wn + j * 16 + quad * 4;
      float4 bv = {0.f, 0.f, 0.f, 0.f};
      if (SPLITS == 1 || blockIdx.z == 0) bv = *(const float4*)&bias[n0 + cb];
      #pragma unroll
      for (int i = 0; i < 4; ++i) {
        float v0 = acc[i][j][0] + bv.x;
        float v1 = acc[i][j][1] + bv.y;
        float v2 = acc[i][j][2] + bv.z;
        float v3 = acc[i][j][3] + bv.w;
        if (GELU) {
          v0 = 0.5f * v0 * (1.0f + erff(v0 * 0.70710678118654752f));
          v1 = 0.5f * v1 * (1.0f + erff(v1 * 0.70710678118654752f));
          v2 = 0.5f * v2 * (1.0f + erff(v2 * 0.70710678118654752f));
          v3 = 0.5f * v3 * (1.0f + erff(v3 * 0.70710678118654752f));
        }
        ushort4 pk;
        pk.x = f2bu(v0); pk.y = f2bu(v1); pk.z = f2bu(v2); pk.w = f2bu(v3);
        *(ushort4*)&eps[(wm + i * 16 + rsel) * EPS_LD + cb] = pk;
      }
    }
    __syncthreads();
    const size_t zb = (SPLITS > 1) ? (size_t)blockIdx.z * M * N : 0;
    #pragma unroll
    for (int it = 0; it < 8; ++it) {
      int row = it * (BM / 8) + (tid >> 4);
      int c = tid & 15;
      bf16x8 v = *(const bf16x8*)&eps[row * EPS_LD + c * 8];
      *(bf16x8*)&Cout[zb + (size_t)(m0 + row) * N + n0 + c * 8] = v;
    }
  } else {
    // value(i,j,r) = C[m0+wm+i*16+quad*4+r][n0+wn+j*16+rsel]; LDS tile is [n][m]
    #pragma unroll
    for (int j = 0; j < 4; ++j) {
      float bv = bias[n0 + wn + j * 16 + rsel];
      #pragma unroll
      for (int i = 0; i < 4; ++i) {
        ushort4 pk;
        pk.x = f2bu(acc[i][j][0] + bv);
        pk.y = f2bu(acc[i][j][1] + bv);
        pk.z = f2bu(acc[i][j][2] + bv);
        pk.w = f2bu(acc[i][j][3] + bv);
        *(ushort4*)&eps[(wn + j * 16 + rsel) * EPS_LD + wm + i * 16 + quad * 4] = pk;
      }
    }
    __syncthreads();
    #pragma unroll
    for (int it = 0; it < 8; ++it) {
      int row, c;
      if (BM == 64) { row = it * 16 + (tid >> 3); c = tid & 7; }
      else          { row = it * 16 + (tid >> 4); c = tid & 15; }
      bf16x8 v = *(const bf16x8*)&eps[row * EPS_LD + c * 8];
      *(bf16x8*)&vTout[(size_t)(n0 - 1536 + row) * CS + m0 + c * 8] = v;
    }
  }
}

template<int BM, int GELU, int SPLITS, int VTFUSE>
__global__ __launch_bounds__(BM * 2, BM == 64 ? 3 : 2) void gemm_mfma(
    const bf16* __restrict__ A, const bf16* __restrict__ Bt,
    const float* __restrict__ bias, bf16* __restrict__ Cout,
    bf16* __restrict__ vTout, int M, int N, int Ktot) {
  // dbuf staging: BM=64 -> 48KB; BM=128 -> 64KB. eps aliases (max 34816B).
  __shared__ __align__(16) char smem[BM * 256 + 32768];
  int nx = gridDim.x, ny = gridDim.y;
  int nwg = nx * ny;
  int orig = blockIdx.x + blockIdx.y * nx;
  int bx, by;
  if (nwg & 7) { bx = blockIdx.x; by = blockIdx.y; }
  else {
    int q8 = nwg >> 3;
    int nid = (orig & 7) * q8 + (orig >> 3);
    bx = nid / ny; by = nid - bx * ny;
  }
  if (VTFUSE && bx * 128 >= 1536)
    gemm_body<BM, 0, 1, 1>(A, Bt, bias, Cout, vTout, M, N, Ktot, smem, bx, by);
  else
    gemm_body<BM, GELU, SPLITS, 0>(A, Bt, bias, Cout, vTout, M, N, Ktot, smem, bx, by);
}

// ---------------- MFMA flash attention v3: 2-phase double-buffered K/V ----------
// Round-5's proven GEMM schedule ported to attn: STAGE(kt+1) issued right after
// the tile-ready barrier, compute(kt) overlaps its latency. Buffer overwritten
// by STAGE(kt+1) is the one read at compute(kt-1), finished before the barrier.
// Barrier skeleton is block-uniform: STAGE gating (tin) depends only on q0/kt;
// per-wave 'active' gates compute only.
__global__ __launch_bounds__(256) void attn_mfma(
    const bf16* __restrict__ qkv, const bf16* __restrict__ vT,
    const int* __restrict__ mask, bf16* __restrict__ ctx) {
  __shared__ __align__(16) bf16 Ks[2][64 * 64];
  __shared__ __align__(16) bf16 Vs[2][64 * 64];
  __shared__ __align__(16) bf16 Ps[4][16][72];
  const int h = blockIdx.y;
  const int q0 = blockIdx.x * 64;
  const int tid = threadIdx.x;
  const int wv = tid >> 6, lane = tid & 63;
  const int quad = lane >> 4, rsel = lane & 15;
  const int rx = rsel & 7;
  const int qw = q0 + wv * 16;
  const int r_in = lane >> 3, chunk = lane & 7, gchunk = chunk ^ r_in;

  const bf16* qp = &qkv[(size_t)(qw + rsel) * QKVN + h * CDH + quad * 8];
  bf16x8 qf0 = *(const bf16x8*)qp;
  bf16x8 qf1 = *(const bf16x8*)(qp + 32);

  float mi[4], li[4];
  f32x4 o[4] = {};
  #pragma unroll
  for (int r = 0; r < 4; ++r) { mi[r] = -1e30f; li[r] = 0.f; }

  auto STAGE = [&](int buf, int kt) {
    int kbase = q0 - CW + kt * 64;
    #pragma unroll
    for (int i = 0; i < 4; ++i) {
      int op = wv * 4 + i;     // 0..15: 8 K ops + 8 V ops
      if (op < 8) {
        int krow = min(max(kbase + op * 8 + r_in, 0), CS - 1);
        gload_lds16(&qkv[(size_t)krow * QKVN + 768 + h * CDH + gchunk * 8], &Ks[buf][op * 512]);
      } else {
        int vop = op - 8;
        int kc = min(max(kbase + gchunk * 8, 0), CS - 8);
        gload_lds16(&vT[(size_t)(h * CDH + vop * 8 + r_in) * CS + kc], &Vs[buf][vop * 512]);
      }
    }
  };
  auto tin = [&](int kt) {
    int kbase = q0 - CW + kt * 64;
    return (kbase + 63 >= 0) && (kbase < CS);
  };

  if (tin(0)) STAGE(0, 0);

  #pragma unroll 1
  for (int kt = 0; kt < 9; ++kt) {
    // current buffer landed; all waves done with compute(kt-1)
    __asm__ volatile("s_waitcnt vmcnt(0)" ::: "memory");
    __builtin_amdgcn_s_barrier();
    __builtin_amdgcn_sched_barrier(0);
    if (kt < 8 && tin(kt + 1)) STAGE((kt + 1) & 1, kt + 1);  // prefetch (async)
    __builtin_amdgcn_sched_barrier(0);

    int kbase = q0 - CW + kt * 64;
    bool active = tin(kt) && (kbase + 63 >= qw - CW) && (kbase <= qw + 15 + CW);
    if (active) {
      const bf16* Kb = Ks[kt & 1];
      const bf16* Vb = Vs[kt & 1];
      f32x4 sc[4];
      #pragma unroll
      for (int nt = 0; nt < 4; ++nt) {
        const bf16* kp = &Kb[(nt * 16 + rsel) * 64];
        bf16x8 kf0 = *(const bf16x8*)(kp + (quad ^ rx) * 8);
        bf16x8 kf1 = *(const bf16x8*)(kp + ((quad + 4) ^ rx) * 8);
        f32x4 z = {};
        __builtin_amdgcn_s_setprio(1);
        z = __builtin_amdgcn_mfma_f32_16x16x32_bf16(qf0, kf0, z, 0, 0, 0);
        z = __builtin_amdgcn_mfma_f32_16x16x32_bf16(qf1, kf1, z, 0, 0, 0);
        __builtin_amdgcn_s_setprio(0);
        sc[nt] = z;
      }
      float mx[4] = {-1e30f, -1e30f, -1e30f, -1e30f};
      #pragma unroll
      for (int nt = 0; nt < 4; ++nt) {
        int pp = kbase + nt * 16 + rsel;
        int ppc = min(max(pp, 0), CS - 1);
        bool kvld = (pp >= 0) && (pp < CS) && (mask[ppc] != 0);
        #pragma unroll
        for (int r = 0; r < 4; ++r) {
          int qr = qw + quad * 4 + r;
          float s = sc[nt][r] * 0.125f;
          bool band = (pp >= qr - CW) && (pp <= qr + CW);
          s = (kvld && band) ? s : -1e9f;
          sc[nt][r] = s;
          mx[r] = fmaxf(mx[r], s);
        }
      }
      #pragma unroll
      for (int r = 0; r < 4; ++r) {
        #pragma unroll
        for (int off = 1; off < 16; off <<= 1)
          mx[r] = fmaxf(mx[r], __shfl_xor(mx[r], off, 64));
      }
      float al[4], rs[4] = {};
      #pragma unroll
      for (int r = 0; r < 4; ++r) {
        float mn = fmaxf(mi[r], mx[r]);
        al[r] = __expf(mi[r] - mn);
        mi[r] = mn;
      }
      #pragma unroll
      for (int nt = 0; nt < 4; ++nt)
        #pragma unroll
        for (int r = 0; r < 4; ++r) {
          float p = __expf(sc[nt][r] - mi[r]);
          sc[nt][r] = p;
          rs[r] += p;
        }
      #pragma unroll
      for (int r = 0; r < 4; ++r) {
        #pragma unroll
        for (int off = 1; off < 16; off <<= 1)
          rs[r] += __shfl_xor(rs[r], off, 64);
        li[r] = li[r] * al[r] + rs[r];
      }
      #pragma unroll
      for (int d = 0; d < 4; ++d)
        #pragma unroll
        for (int r = 0; r < 4; ++r) o[d][r] *= al[r];
      #pragma unroll
      for (int nt = 0; nt < 4; ++nt)
        #pragma unroll
        for (int r = 0; r < 4; ++r)
          Ps[wv][quad * 4 + r][nt * 16 + rsel] = __float2bfloat16(sc[nt][r]);
      __asm__ volatile("s_waitcnt lgkmcnt(0)" ::: "memory");
      __builtin_amdgcn_sched_barrier(0);
      bf16x8 pf0 = *(const bf16x8*)&Ps[wv][rsel][quad * 8];
      bf16x8 pf1 = *(const bf16x8*)&Ps[wv][rsel][32 + quad * 8];
      #pragma unroll
      for (int d = 0; d < 4; ++d) {
        const bf16* vr = &Vb[(d * 16 + rsel) * 64];
        bf16x8 vf0 = *(const bf16x8*)(vr + (quad ^ rx) * 8);
        bf16x8 vf1 = *(const bf16x8*)(vr + ((quad + 4) ^ rx) * 8);
        __builtin_amdgcn_s_setprio(1);
        o[d] = __builtin_amdgcn_mfma_f32_16x16x32_bf16(pf0, vf0, o[d], 0, 0, 0);
        o[d] = __builtin_amdgcn_mfma_f32_16x16x32_bf16(pf1, vf1, o[d], 0, 0, 0);
        __builtin_amdgcn_s_setprio(0);
      }
    }
  }

  // epilogue: normalize, stage bf16 in own Ps plane (wave-private), 16B stores
  float inv[4];
  #pragma unroll
  for (int r = 0; r < 4; ++r) inv[r] = 1.0f / li[r];
  #pragma unroll
  for (int d = 0; d < 4; ++d)
    #pragma unroll
    for (int r = 0; r < 4; ++r)
      Ps[wv][quad * 4 + r][d * 16 + rsel] = __float2bfloat16(o[d][r] * inv[r]);
  __asm__ volatile("s_waitcnt lgkmcnt(0)" ::: "memory");
  __builtin_amdgcn_sched_barrier(0);
  #pragma unroll
  for (int it = 0; it < 2; ++it) {
    int row = it * 8 + (lane >> 3);
    bf16x8 vv = *(const bf16x8*)&Ps[wv][row][(lane & 7) * 8];
    *(bf16x8*)&ctx[(size_t)(qw + row) * CD + h * CDH + (lane & 7) * 8] = vv;
  }
}

// ---------------- xout = LN(xin + sum_p g[p](bf16)); also writes xb ----------------
template<int P>
__global__ __launch_bounds__(192) void add_ln_kernel(
    const bf16* __restrict__ g, const float* __restrict__ xin,
    float* __restrict__ xout, bf16* __restrict__ xb,
    const float* __restrict__ gs, const float* __restrict__ gb) {
  __shared__ float red[3];
  int srow = blockIdx.x;
  int d = threadIdx.x * 4;
  size_t base = (size_t)srow * CD + d;
  float4 a = *(const float4*)&xin[base];
  #pragma unroll
  for (int p = 0; p < P; ++p) {
    ushort4 gg = *(const ushort4*)&g[p * SDC + base];
    a.x += bu2f(gg.x); a.y += bu2f(gg.y); a.z += bu2f(gg.z); a.w += bu2f(gg.w);
  }
  float sum = block_reduce_sum<3>(a.x + a.y + a.z + a.w, red);
  float mean = sum * (1.0f / CD);
  float cx = a.x - mean, cy = a.y - mean, cz = a.z - mean, cw = a.w - mean;
  float sq = block_reduce_sum<3>(cx * cx + cy * cy + cz * cz + cw * cw, red);
  float rstd = rsqrtf(sq * (1.0f / CD) + 1e-5f);
  float4 g4 = *(const float4*)&gs[d];
  float4 b4 = *(const float4*)&gb[d];
  float4 o;
  o.x = cx * rstd * g4.x + b4.x;
  o.y = cy * rstd * g4.y + b4.y;
  o.z = cz * rstd * g4.z + b4.z;
  o.w = cw * rstd * g4.w + b4.w;
  *(float4*)&xout[base] = o;
  ushort4 pk;
  pk.x = f2bu(o.x); pk.y = f2bu(o.y); pk.z = f2bu(o.z); pk.w = f2bu(o.w);
  *(ushort4*)&xb[base] = pk;
}

// ---------------- pooled = tanh(x[0] @ pool_W + pool_b) ----------------
__global__ __launch_bounds__(256) void pool_kernel(
    const float* __restrict__ x, const float* __restrict__ Wp,
    const float* __restrict__ bp, float* __restrict__ out) {
  __shared__ float xs[CD];
  __shared__ float red[4][64];
  int t = threadIdx.x;
  for (int i = t; i < CD; i += 256) xs[i] = x[i];
  __syncthreads();
  int n = blockIdx.x * 64 + (t & 63);
  int kp = t >> 6;
  float acc = 0.f;
  #pragma unroll 4
  for (int kk = kp * 192; kk < kp * 192 + 192; ++kk)
    acc = fmaf(xs[kk], Wp[(size_t)kk * CD + n], acc);
  red[kp][t & 63] = acc;
  __syncthreads();
  if (t < 64) {
    int nn = blockIdx.x * 64 + t;
    out[nn] = tanhf(red[0][t] + red[1][t] + red[2][t] + red[3][t] + bp[nn]);
  }
}

extern "C" void kernel_launch(void* const* d_in, const int* in_sizes, int n_in,
                              void* d_out, int out_size, void* d_ws, size_t ws_size,
                              hipStream_t stream) {
  const int*   ids   = (const int*)d_in[0];
  const int*   mask  = (const int*)d_in[1];
  const float* wemb  = (const float*)d_in[2];
  const float* pemb  = (const float*)d_in[3];
  const float* temb  = (const float*)d_in[4];
  const float* elns  = (const float*)d_in[5];
  const float* elnb  = (const float*)d_in[6];
  const float* Wqkv  = (const float*)d_in[7];
  const float* bqkv  = (const float*)d_in[8];
  const float* Wo    = (const float*)d_in[9];
  const float* bo    = (const float*)d_in[10];
  const float* ln1s  = (const float*)d_in[11];
  const float* ln1b  = (const float*)d_in[12];
  const float* W1    = (const float*)d_in[13];
  const float* b1    = (const float*)d_in[14];
  const float* W2    = (const float*)d_in[15];
  const float* b2    = (const float*)d_in[16];
  const float* ln2s  = (const float*)d_in[17];
  const float* ln2b  = (const float*)d_in[18];
  const float* poolW = (const float*)d_in[19];
  const float* poolb = (const float*)d_in[20];

  const size_t SD = SDC;
  const size_t SF = (size_t)CS * CF;

  char* w = (char*)d_ws;
  float* x    = (float*)w; w += SD * 4;
  bf16*  xb   = (bf16*)w;  w += SD * 2;
  bf16*  qkv  = (bf16*)w;  w += (size_t)CS * QKVN * 2;
  bf16*  vT   = (bf16*)w;  w += SD * 2;
  bf16*  ctxb = (bf16*)w;  w += SD * 2;
  bf16*  t1b  = (bf16*)w;  w += SF * 2;
  bf16*  t2   = (bf16*)w;  w += SD * 2 * 4;   // split-K bf16 partials
  bf16* WqkvT = (bf16*)w;  w += (size_t)CL * QKVN * CD * 2;
  bf16* WoT   = (bf16*)w;  w += (size_t)CL * CD * CD * 2;
  bf16* W1T   = (bf16*)w;  w += (size_t)CL * CF * CD * 2;
  bf16* W2T   = (bf16*)w;  w += (size_t)CL * CD * CF * 2;

  prep_kernel<<<6912 + CS, 256, 0, stream>>>(
      Wqkv, Wo, W1, W2, WqkvT, WoT, W1T, W2T,
      ids, mask, wemb, pemb, temb, elns, elnb, x, xb);

  for (int l = 0; l < CL; ++l) {
    gemm_mfma<128,0,1,1><<<dim3(QKVN/128, CS/128), 256, 0, stream>>>(
        xb, WqkvT + (size_t)l * QKVN * CD, bqkv + (size_t)l * 3 * CD, qkv, vT, CS, QKVN, CD);
    attn_mfma<<<dim3(CS/64, CH), 256, 0, stream>>>(qkv, vT, mask, ctxb);
    gemm_mfma<64,0,2,0><<<dim3(CD/128, CS/64, 2), 128, 0, stream>>>(
        ctxb, WoT + (size_t)l * CD * CD, bo + (size_t)l * CD, t2, nullptr, CS, CD, CD);
    add_ln_kernel<2><<<CS, 192, 0, stream>>>(t2, x, x, xb,
        ln1s + (size_t)l * CD, ln1b + (size_t)l * CD);
    gemm_mfma<128,1,1,0><<<dim3(CF/128, CS/128), 256, 0, stream>>>(
        xb, W1T + (size_t)l * CF * CD, b1 + (size_t)l * CF, t1b, nullptr, CS, CF, CD);
    gemm_mfma<64,0,2,0><<<dim3(CD/128, CS/64, 2), 128, 0, stream>>>(
        t1b, W2T + (size_t)l * CD * CF, b2 + (size_t)l * CD, t2, nullptr, CS, CD, CF);
    float* lastx = (l == CL - 1) ? (float*)d_out : x;
    add_ln_kernel<2><<<CS, 192, 0, stream>>>(t2, x, lastx, xb,
        ln2s + (size_t)l * CD, ln2b + (size_t)l * CD);
  }

  pool_kernel<<<12, 256, 0, stream>>>((float*)d_out, poolW, poolb, (float*)d_out + SD);
}